// Round 5
// baseline (554.498 us; speedup 1.0000x reference)
//
#include <hip/hip_runtime.h>

// Problem constants (from reference)
constexpr int T = 2048;
constexpr int B = 256;
constexpr int V = 90;
constexpr int P = 89;   // V - 1
constexpr int IGNORE = 999;
constexpr float EPS = 1e-28f;

constexpr size_t SZ_FS = (size_t)T * B * V;   // 47185920 floats
constexpr size_t SZ_P  = (size_t)T * B * P;   // 46661632 floats
constexpr int PAD = 18;                       // LDS row stride (words): even => b64-aligned

// R6 HYBRID. Model calibrated on two anchors:
//  * R0 thread-per-row = TA-bound (~440K line-req/CU == 437K cyc measured):
//    scattered loads, BCE wave-max loop.
//  * R5 wave-per-row = ISSUE-bound (~136 busy-cyc/row x 2048 rows/CU = 278K
//    ~= 0.79 x 353K wall): one wave's whole instr stream per row.
// Hybrid: stage [64 rows][16 ch] chunks coalesced global->LDS (8-16 instrs,
// ~12 lines each), compute THREAD-per-row from LDS (per-row issue ~60 cyc,
// no cross-lane ops, no wave-max loop waste on loads). LDS transpose cost
// rides the parallel LDS pipe. Per-wave tiles -> no __syncthreads in loop.
// 2 LDS buffers/wave (CE reuses ps buffer) = 36 KB/block -> 4 blocks/CU.
template <int CTRL>
__device__ __forceinline__ float dpp_add(float v) {
    int t = __builtin_amdgcn_update_dpp(0, __float_as_int(v), CTRL, 0xf, 0xf, true);
    return v + __int_as_float(t);
}
__device__ __forceinline__ float wave_sum_uniform(float v) {
    v = dpp_add<0x111>(v);  // row_shr:1
    v = dpp_add<0x112>(v);  // row_shr:2
    v = dpp_add<0x114>(v);  // row_shr:4
    v = dpp_add<0x118>(v);  // row_shr:8
    v = dpp_add<0x142>(v);  // row_bcast15
    v = dpp_add<0x143>(v);  // row_bcast31 -> lane 63 has full sum
    return __int_as_float(__builtin_amdgcn_readlane(__float_as_int(v), 63));
}

__global__ __launch_bounds__(256) void trans_inv_loss_kernel(
    const float* __restrict__ first_scores,   // [T,B,V]
    const float* __restrict__ pattern_scores, // [T,B,P]
    const int*   __restrict__ first_targs,    // [T,B]
    const float* __restrict__ pattern_targs,  // [T,B,P]
    const int*   __restrict__ lengths,        // [B]
    float*       __restrict__ out)            // [1]
{
    const int lane  = threadIdx.x & 63;
    const int wid   = threadIdx.x >> 6;
    const int gwave = blockIdx.x * 4 + wid;
    const int r0    = gwave * 64;             // wave's 64-row slab (same t: r0 is 64-aligned)
    const int row   = r0 + lane;              // THIS thread's row
    const int t     = r0 >> 8;

    __shared__ float lds[4][2][64 * PAD];     // 36 KB: per wave bufA, bufB
    float* bufA = lds[wid][0];
    float* bufB = lds[wid][1];

    // Per-thread metadata + target-logit gather (scattered, 1 instr — in flight early)
    const int   targ  = first_targs[row];                    // coalesced
    const int   len   = lengths[row & (B - 1)];              // coalesced (b == row&255)
    const int   ct    = ((unsigned)targ < (unsigned)V) ? targ : 0;
    const float xt    = first_scores[(size_t)row * V + ct];  // gather: 64 lines/tile, once
    const int   km    = P - targ;
    const int   ekmax = (t < len) ? (km > 0 ? km : 0) : 0;   // BCE channel bound

    const int srow = lane >> 3;        // sub-row 0..7 within a k-step
    const int scol = (lane & 7) * 2;   // even col 0..14 within chunk

    // ---------------- CE: sum(exp) over 90 logits, thread-per-row ----------------
    const float* fs_t = first_scores + (size_t)r0 * V;
    float s = 0.0f;
    #pragma unroll
    for (int ck = 0; ck < 6; ++ck) {
        const int c0 = ck * 16;
        float2 tmp[8];
        #pragma unroll
        for (int k = 0; k < 8; ++k) {          // stage [64][16]: 8 coalesced float2/lane
            size_t e = (size_t)(k * 8 + srow) * V + (c0 + scol);
            if (ck == 5) {                     // clamp at global end (last rows read cols 90..95)
                size_t eg = (size_t)r0 * V + e;
                if (eg > SZ_FS - 2) e -= (eg - (SZ_FS - 2));
            }
            tmp[k] = *(const float2*)(fs_t + e);
        }
        #pragma unroll
        for (int k = 0; k < 8; ++k)
            *(float2*)&bufA[(k * 8 + srow) * PAD + scol] = tmp[k];
        __asm__ volatile("s_waitcnt lgkmcnt(0)" ::: "memory");
        #pragma unroll
        for (int j = 0; j < 8; ++j) {          // read own row; ck==5 keeps cols 80..89 only
            if (ck == 5 && j >= 5) break;
            float2 v = *(const float2*)&bufA[lane * PAD + 2 * j];
            s += __expf(v.x) + __expf(v.y);
        }
    }
    float acc = (targ != IGNORE) ? (__logf(s) - xt) : 0.0f;

    // ---------------- BCE: masked prefix over 89 channels, thread-per-row --------
    const float* ps_t = pattern_scores + (size_t)r0 * P;
    const float* pt_t = pattern_targs  + (size_t)r0 * P;
    #pragma unroll
    for (int ck = 0; ck < 6; ++ck) {
        const int c0 = ck * 16;
        if (__ballot(ekmax > c0) == 0) break;  // wave-uniform early exit
        float a0[8], a1[8], b0[8], b1[8];
        #pragma unroll
        for (int k = 0; k < 8; ++k) {          // stage ps+pt [64][16] (b32: 89-stride rows
            size_t e = (size_t)(k * 8 + srow) * P + (c0 + scol);   //  are odd => no b64 src)
            if (ck == 5) {
                size_t eg = (size_t)r0 * P + e;
                if (eg > SZ_P - 2) e -= (eg - (SZ_P - 2));
            }
            a0[k] = ps_t[e]; a1[k] = ps_t[e + 1];
            b0[k] = pt_t[e]; b1[k] = pt_t[e + 1];
        }
        #pragma unroll
        for (int k = 0; k < 8; ++k) {
            *(float2*)&bufA[(k * 8 + srow) * PAD + scol] = make_float2(a0[k], a1[k]);
            *(float2*)&bufB[(k * 8 + srow) * PAD + scol] = make_float2(b0[k], b1[k]);
        }
        __asm__ volatile("s_waitcnt lgkmcnt(0)" ::: "memory");
        #pragma unroll
        for (int j = 0; j < 8; ++j) {
            float2 p = *(const float2*)&bufA[lane * PAD + 2 * j];
            float2 y = *(const float2*)&bufB[lane * PAD + 2 * j];
            const int c = c0 + 2 * j;
            float l1 = __logf(p.x + EPS);
            float l2 = __logf(1.0f - p.x + EPS);
            float v0 = y.x * (l1 - l2) + l2;       // = y*l1 + (1-y)*l2
            float l3 = __logf(p.y + EPS);
            float l4 = __logf(1.0f - p.y + EPS);
            float v1 = y.y * (l3 - l4) + l4;
            if (c < ekmax)     acc -= v0;          // garbage cols (>=89 / clamped dup)
            if (c + 1 < ekmax) acc -= v1;          //  excluded: ekmax <= 89
        }
    }

    // ---- reduce: DPP wave sum -> LDS -> one atomicAdd per block ----
    const float wtot = wave_sum_uniform(acc);
    __shared__ float wsum[4];
    if (lane == 0) wsum[wid] = wtot;
    __syncthreads();
    if (threadIdx.x == 0)
        atomicAdd(out, (wsum[0] + wsum[1] + wsum[2] + wsum[3]) * (1.0f / (float)B));
}

extern "C" void kernel_launch(void* const* d_in, const int* in_sizes, int n_in,
                              void* d_out, int out_size, void* d_ws, size_t ws_size,
                              hipStream_t stream) {
    const float* first_scores   = (const float*)d_in[0];
    const float* pattern_scores = (const float*)d_in[1];
    const int*   first_targs    = (const int*)  d_in[2];
    const float* pattern_targs  = (const float*)d_in[3];
    const int*   lengths        = (const int*)  d_in[4];
    float* out = (float*)d_out;

    // d_out is poisoned before every timed launch -> zero it ourselves.
    (void)hipMemsetAsync(out, 0, sizeof(float) * (size_t)out_size, stream);

    dim3 block(256);                          // 4 waves/block, per-wave 64-row tiles
    dim3 grid((T * B) / (4 * 64));            // 2048 blocks
    trans_inv_loss_kernel<<<grid, block, 0, stream>>>(
        first_scores, pattern_scores, first_targs, pattern_targs, lengths, out);
}